// Round 6
// baseline (5458.434 us; speedup 1.0000x reference)
//
#include <hip/hip_runtime.h>

// Problem dims
#define T_ 512
#define B_ 64
#define E_ 256
#define H_ 256
#define K_ 21
#define NSLICE 16   // workgroups per direction (16 hidden units each)

typedef short          s16x8 __attribute__((ext_vector_type(8)));
typedef unsigned short u16x4 __attribute__((ext_vector_type(4)));
typedef float          f32x4 __attribute__((ext_vector_type(4)));

// ---- module-scope device scratch (d_out is float32; d_ws unused) ----
__device__ __attribute__((aligned(16))) unsigned short g_hs[T_ * B_ * 2 * H_];  // [T][B][2H] bf16 bits
__device__ __attribute__((aligned(16))) unsigned short g_hbuf[2 * 2 * B_ * H_]; // [dir][par][B][H]
__device__ __attribute__((aligned(16))) float    g_em[T_ * B_ * K_];            // [T][B][K] f32
__device__ unsigned g_ctr[2 * T_];                                              // [dir][T]
// ---- diagnostics: every failure mode -> distinct loss-slot value ----
__device__ int   g_marker;
__device__ int   g_done_lstm;   // expect 32
__device__ int   g_done_dec;    // expect 128
__device__ int   g_timeout;
__device__ float g_sum;

__device__ __forceinline__ f32x4 mfma16(s16x8 a, s16x8 b, f32x4 c) {
  return __builtin_amdgcn_mfma_f32_16x16x32_bf16(a, b, c, 0, 0, 0);
}

// f32 -> bf16 bits, round-to-nearest-even (finite inputs only)
__device__ __forceinline__ unsigned short f2b(float f) {
  unsigned u = __float_as_uint(f);
  u = (u + 0x7fffu + ((u >> 16) & 1u)) >> 16;
  return (unsigned short)u;
}

__device__ __forceinline__ s16x8 cvt8(const float* p) {
  s16x8 v;
#pragma unroll
  for (int j = 0; j < 8; ++j) v[j] = (short)f2b(p[j]);
  return v;
}

// ---------------- K0: zero h-exchange buffers, counters, diagnostics ----------------
__global__ void k_zero() {
  int i = blockIdx.x * 256 + threadIdx.x;   // 256 x 256 = 65536 threads
  if (i < 2 * 2 * B_ * H_) g_hbuf[i] = 0;
  if (i < 2 * T_) g_ctr[i] = 0u;
  if (i == 0) {
    g_marker = 1;
    g_done_lstm = 0;
    g_done_dec = 0;
    g_timeout = 0;
    g_sum = 0.f;
  }
}

// ---------------- K1: biLSTM recurrence (MFMA, weights stationary in VGPRs) ----------
// 32 WGs: dir = wg&1, slice s = wg>>1 (16 hidden units each). 256 thr = 4 waves.
// Per step: G = [h_{t-1} | xe_t] @ Wslice^T via mfma_f32_16x16x32_bf16 (fp32 acc);
// gates in fp32; h slice published to g_hbuf (double-buffered by step parity) with
// __threadfence + device-scope atomic counters (cross-XCD safe); h also stored to g_hs.
__global__ __launch_bounds__(256, 1) void k_lstm(
    const int* __restrict__ x, const float* __restrict__ emb,
    const float* __restrict__ whh_f, const float* __restrict__ wih_f, const float* __restrict__ b_f,
    const float* __restrict__ whh_b, const float* __restrict__ wih_b, const float* __restrict__ b_b)
{
  const int wg  = blockIdx.x;
  const int dir = wg & 1;
  const int s   = wg >> 1;
  const int tid = threadIdx.x;
  const int lane = tid & 63;
  const int wv  = tid >> 6;      // 0..3
  const int wm  = wv & 1;        // M half (batches wm*32..+31)
  const int wn  = wv >> 1;       // N half (gate-rows wn*32..+31)
  const int l15 = lane & 15;
  const int l4  = lane >> 4;

  const float* whh  = dir ? whh_b : whh_f;
  const float* wih  = dir ? wih_b : wih_f;
  const float* bias = dir ? b_b : b_f;
  unsigned short* hb = g_hbuf + (size_t)dir * (2 * B_ * H_);
  unsigned* ct = g_ctr + dir * T_;

  // stationary weight B-fragments: n = 64 gate-rows (4 gates x 16 units), k = [h|xe] (512)
  // B[k][n]: n = lane&15, k = (lane>>4)*8 + j
  s16x8 bfr[2][16];
#pragma unroll
  for (int ni = 0; ni < 2; ++ni) {
    int nl = (2 * wn + ni) * 16 + l15;     // 0..63
    int q = nl >> 4, j = nl & 15;          // gate, unit-within-slice
    int grow = q * H_ + s * 16 + j;        // row in [4H]
    const float* wr_h = whh + (size_t)grow * H_;
    const float* wr_i = wih + (size_t)grow * E_;
#pragma unroll
    for (int kc = 0; kc < 16; ++kc) {
      int k = kc * 32 + l4 * 8;
      const float* src = (k < H_) ? (wr_h + k) : (wr_i + (k - H_));
      bfr[ni][kc] = cvt8(src);
    }
  }

  // epilogue mapping: thread -> (batch em_m, 4 units em_jg*4..+3)
  const int em_m  = tid >> 2;
  const int em_jg = tid & 3;
  float bq[4][4];
#pragma unroll
  for (int q = 0; q < 4; ++q)
#pragma unroll
    for (int p = 0; p < 4; ++p) bq[q][p] = bias[q * H_ + s * 16 + em_jg * 4 + p];
  float cst[4] = {0.f, 0.f, 0.f, 0.f};

  __shared__ float G[64 * 65];

  const int am0 = wm * 32 + l15;        // A rows: m = lane&15 (+16 per sub-tile)
  const int am1 = wm * 32 + 16 + l15;

  // prologue: xe fragments for step 0 (A[m][k]: m = lane&15, k = (lane>>4)*8 + j)
  s16x8 xa0[8], xa1[8];
  {
    int t0 = dir ? (T_ - 1) : 0;
    int r0 = x[am0 * T_ + t0];
    int r1 = x[am1 * T_ + t0];
    const float* e0 = emb + (size_t)r0 * E_;
    const float* e1 = emb + (size_t)r1 * E_;
#pragma unroll
    for (int kc = 0; kc < 8; ++kc) {
      xa0[kc] = cvt8(e0 + kc * 32 + l4 * 8);
      xa1[kc] = cvt8(e1 + kc * 32 + l4 * 8);
    }
  }

  for (int step = 0; step < T_; ++step) {
    const int t = dir ? (T_ - 1 - step) : step;
    const int par = step & 1;

    int r0n = 0, r1n = 0;
    if (step + 1 < T_) {
      int tn = dir ? (T_ - 2 - step) : (step + 1);
      r0n = x[am0 * T_ + tn];
      r1n = x[am1 * T_ + tn];
    }

    if (step > 0) {
      if (tid == 0) {
        int it = 0;
        // atomic RMW poll reaches the device coherence point (cross-XCD safe); bounded.
        while (atomicAdd(&ct[step - 1], 0u) < (unsigned)NSLICE) {
          if (++it > (1 << 20)) { atomicAdd(&g_timeout, 1); break; }
        }
      }
      __syncthreads();
      __threadfence();   // acquire: invalidate caches before reading peers' h
    }

    const unsigned short* hsrc = hb + (1 - par) * (B_ * H_);
    const unsigned short* h0p = hsrc + am0 * H_ + l4 * 8;
    const unsigned short* h1p = hsrc + am1 * H_ + l4 * 8;

    f32x4 acc00 = {0,0,0,0}, acc01 = {0,0,0,0}, acc10 = {0,0,0,0}, acc11 = {0,0,0,0};
#pragma unroll
    for (int kc = 0; kc < 8; ++kc) {        // h half (k = 0..255)
      s16x8 a0 = *(const s16x8*)(h0p + kc * 32);
      s16x8 a1 = *(const s16x8*)(h1p + kc * 32);
      acc00 = mfma16(a0, bfr[0][kc], acc00);
      acc01 = mfma16(a0, bfr[1][kc], acc01);
      acc10 = mfma16(a1, bfr[0][kc], acc10);
      acc11 = mfma16(a1, bfr[1][kc], acc11);
    }
#pragma unroll
    for (int kc = 0; kc < 8; ++kc) {        // xe half (k = 256..511), prefetched
      acc00 = mfma16(xa0[kc], bfr[0][8 + kc], acc00);
      acc01 = mfma16(xa0[kc], bfr[1][8 + kc], acc01);
      acc10 = mfma16(xa1[kc], bfr[0][8 + kc], acc10);
      acc11 = mfma16(xa1[kc], bfr[1][8 + kc], acc11);
    }

    // scatter to LDS: G[m][n]; C/D layout col=lane&15, row=(lane>>4)*4+r
#pragma unroll
    for (int mi = 0; mi < 2; ++mi)
#pragma unroll
      for (int ni = 0; ni < 2; ++ni) {
        f32x4 a = (mi == 0) ? (ni == 0 ? acc00 : acc01) : (ni == 0 ? acc10 : acc11);
#pragma unroll
        for (int r = 0; r < 4; ++r) {
          int m = wm * 32 + mi * 16 + l4 * 4 + r;
          int n = (2 * wn + ni) * 16 + l15;
          G[m * 65 + n] = a[r];
        }
      }
    __syncthreads();

    // gates + state update; publish h slice to hbuf (exchange) and hs (persistent)
    unsigned short* hrow = hb + par * (B_ * H_) + em_m * H_ + s * 16 + em_jg * 4;
    unsigned short* hsro = g_hs + ((size_t)t * B_ + em_m) * (2 * H_) + dir * H_ + s * 16 + em_jg * 4;
    u16x4 hv;
#pragma unroll
    for (int p = 0; p < 4; ++p) {
      int j = em_jg * 4 + p;
      float gi = G[em_m * 65 +  0 + j] + bq[0][p];
      float gf = G[em_m * 65 + 16 + j] + bq[1][p];
      float gg = G[em_m * 65 + 32 + j] + bq[2][p];
      float go = G[em_m * 65 + 48 + j] + bq[3][p];
      float ii = 1.f / (1.f + __expf(-gi));
      float ff = 1.f / (1.f + __expf(-gf));
      float gt = 1.f - 2.f / (__expf(2.f * gg) + 1.f);
      float oo = 1.f / (1.f + __expf(-go));
      float c = ff * cst[p] + ii * gt;
      cst[p] = c;
      float h = oo * (1.f - 2.f / (__expf(2.f * c) + 1.f));
      hv[p] = f2b(h);
    }
    *(u16x4*)hrow = hv;
    *(u16x4*)hsro = hv;

    __syncthreads();   // all waves' stores drained (vmcnt) before release
    if (tid == 0) {
      __threadfence();                 // release: write back before counter bump
      atomicAdd(&ct[step], 1u);        // device-scope by default
    }

    // refill xe fragments for next step
    if (step + 1 < T_) {
      const float* e0 = emb + (size_t)r0n * E_;
      const float* e1 = emb + (size_t)r1n * E_;
#pragma unroll
      for (int kc = 0; kc < 8; ++kc) {
        xa0[kc] = cvt8(e0 + kc * 32 + l4 * 8);
        xa1[kc] = cvt8(e1 + kc * 32 + l4 * 8);
      }
    }
  }

  __syncthreads();
  if (tid == 0) atomicAdd(&g_done_lstm, 1);
}

// ---------------- K2: emissions em[t][b][k] = hs @ wc^T + bc (MFMA, N padded to 32) ----
__global__ __launch_bounds__(256) void k_em(const float* __restrict__ wc,
                                            const float* __restrict__ bc) {
  const int tid = threadIdx.x;
  const int lane = tid & 63;
  const int wv = tid >> 6;
  const int l15 = lane & 15;
  const int l4 = lane >> 4;
  const int row0 = blockIdx.x * 64 + wv * 16;   // (t*64+b) row block

  s16x8 bfr[2][16];
#pragma unroll
  for (int ni = 0; ni < 2; ++ni) {
    int n = ni * 16 + l15;
#pragma unroll
    for (int kc = 0; kc < 16; ++kc) {
      s16x8 v;
      if (n < K_) {
        v = cvt8(wc + (size_t)n * (2 * H_) + kc * 32 + l4 * 8);
      } else {
#pragma unroll
        for (int jj = 0; jj < 8; ++jj) v[jj] = 0;
      }
      bfr[ni][kc] = v;
    }
  }

  f32x4 acc0 = {0,0,0,0}, acc1 = {0,0,0,0};
  const unsigned short* arow = g_hs + (size_t)(row0 + l15) * (2 * H_) + l4 * 8;
#pragma unroll
  for (int kc = 0; kc < 16; ++kc) {
    s16x8 a = *(const s16x8*)(arow + kc * 32);
    acc0 = mfma16(a, bfr[0][kc], acc0);
    acc1 = mfma16(a, bfr[1][kc], acc1);
  }
#pragma unroll
  for (int r = 0; r < 4; ++r) {
    int m = l4 * 4 + r;
    g_em[(size_t)(row0 + m) * K_ + l15] = acc0[r] + bc[l15];       // n0 = l15 < 16 < K
    int n1 = 16 + l15;
    if (n1 < K_) g_em[(size_t)(row0 + m) * K_ + n1] = acc1[r] + bc[n1];
  }
}

// ---------------- K3: decode. blocks 0..63: Viterbi tags; 64..127: CRF llh ----------------
__global__ void k_decode(const int* __restrict__ y,
                         const float* __restrict__ start, const float* __restrict__ endw,
                         const float* __restrict__ trans,
                         float* __restrict__ out_tags) {
  const int id = blockIdx.x;
  const int k = threadIdx.x;   // 64 threads = 1 wave
  const float* em = g_em;
  __shared__ float tr[K_ * K_];
  __shared__ float sc[K_];
  __shared__ unsigned char bp[T_][K_];
  __shared__ short tags[T_];
  __shared__ float zsh;

  for (int i = k; i < K_ * K_; i += 64) tr[i] = trans[i];
  __syncthreads();

  if (id < B_) {
    // ---- Viterbi (argmax ties -> first index, matching jnp.argmax) ----
    const int b = id;
    float score = 0.f;
    if (k < K_) score = start[k] + em[(size_t)b * K_ + k];
    __syncthreads();
    for (int t = 1; t < T_; ++t) {
      if (k < K_) sc[k] = score;
      __syncthreads();
      if (k < K_) {
        float e = em[(size_t)(t * B_ + b) * K_ + k];
        float best = -1e30f; int bi = 0;
        for (int k1 = 0; k1 < K_; ++k1) {
          float v = sc[k1] + tr[k1 * K_ + k];
          if (v > best) { best = v; bi = k1; }
        }
        score = best + e;
        bp[t][k] = (unsigned char)bi;
      }
      __syncthreads();
    }
    if (k < K_) sc[k] = score + endw[k];
    __syncthreads();
    if (k == 0) {
      float best = -1e30f; int bi = 0;
      for (int k1 = 0; k1 < K_; ++k1) if (sc[k1] > best) { best = sc[k1]; bi = k1; }
      short tag = (short)bi;
      tags[T_ - 1] = tag;
      for (int t = T_ - 1; t > 0; --t) { tag = (short)bp[t][tag]; tags[t - 1] = tag; }
    }
    __syncthreads();
    // OUTPUT IS FLOAT32 (reference outputs are int32/f32, not bf16)
    for (int t = k; t < T_; t += 64) out_tags[(size_t)b * T_ + t] = (float)tags[t];
    __syncthreads();
    if (k == 0) atomicAdd(&g_done_dec, 1);
  } else {
    // ---- CRF log-likelihood ----
    const int b = id - B_;
    float al = 0.f;
    if (k < K_) al = start[k] + em[(size_t)b * K_ + k];
    __syncthreads();
    for (int t = 1; t < T_; ++t) {
      if (k < K_) sc[k] = al;
      __syncthreads();
      if (k < K_) {
        float e = em[(size_t)(t * B_ + b) * K_ + k];
        float m = -1e30f;
        for (int k1 = 0; k1 < K_; ++k1) m = fmaxf(m, sc[k1] + tr[k1 * K_ + k]);
        float ssum = 0.f;
        for (int k1 = 0; k1 < K_; ++k1) ssum += __expf(sc[k1] + tr[k1 * K_ + k] - m);
        al = m + __logf(ssum) + e;
      }
      __syncthreads();
    }
    if (k < K_) sc[k] = al + endw[k];
    __syncthreads();
    if (k == 0) {
      float m = -1e30f;
      for (int k1 = 0; k1 < K_; ++k1) m = fmaxf(m, sc[k1]);
      float ssum = 0.f;
      for (int k1 = 0; k1 < K_; ++k1) ssum += __expf(sc[k1] - m);
      zsh = m + __logf(ssum);
    }
    __syncthreads();
    const int* yb = y + b * T_;
    float local = 0.f;
    for (int t = k; t < T_; t += 64) {
      if (t >= 1) {
        int y1 = yb[t], y0 = yb[t - 1];
        local += tr[y0 * K_ + y1] + em[(size_t)(t * B_ + b) * K_ + y1];
      }
    }
    for (int off = 32; off > 0; off >>= 1) local += __shfl_down(local, off, 64);
    if (k == 0) {
      int y0 = yb[0], yl = yb[T_ - 1];
      float num = local + start[y0] + em[(size_t)b * K_ + y0] + endw[yl];
      atomicAdd(&g_sum, (num - zsh) * (1.0f / 64.0f));
      atomicAdd(&g_done_dec, 1);
    }
  }
}

// ---------------- K4: finalize; encode pipeline state into the float loss slot ----------
// error map (vs ref ~ -1560): pass | 1040=timeout | 1240=sum~0 | 1440+32d=lstm
// incomplete | 4440+32d=decode incomplete | 18440=k_zero missing | 1560=nothing ran
__global__ void k_fin(float* __restrict__ out) {
  float v;
  if (g_marker != 1)             v = -20000.f;
  else if (g_done_lstm < 32)     v = -3000.f - 32.f * (float)g_done_lstm;
  else if (g_done_dec < 128)     v = -6000.f - 32.f * (float)g_done_dec;
  else if (g_timeout != 0)       v = -2600.f;
  else if (fabsf(g_sum) <= 0.5f) v = -2800.f;
  else                           v = g_sum;
  out[0] = v;
}

extern "C" void kernel_launch(void* const* d_in, const int* in_sizes, int n_in,
                              void* d_out, int out_size, void* d_ws, size_t ws_size,
                              hipStream_t stream) {
  const int*   x     = (const int*)d_in[0];
  const int*   y     = (const int*)d_in[1];
  // d_in[2] = masks: all-true by construction -> unused
  const float* emb   = (const float*)d_in[3];
  const float* wih_f = (const float*)d_in[4];
  const float* whh_f = (const float*)d_in[5];
  const float* b_f   = (const float*)d_in[6];
  const float* wih_b = (const float*)d_in[7];
  const float* whh_b = (const float*)d_in[8];
  const float* b_b   = (const float*)d_in[9];
  const float* wc    = (const float*)d_in[10];
  const float* bc    = (const float*)d_in[11];
  const float* start = (const float*)d_in[12];
  const float* endw  = (const float*)d_in[13];
  const float* trans = (const float*)d_in[14];

  float* out_f = (float*)d_out;   // float32: tags [0..B*T), loss at [B*T]

  k_zero<<<256, 256, 0, stream>>>();
  k_lstm<<<32, 256, 0, stream>>>(x, emb, whh_f, wih_f, b_f, whh_b, wih_b, b_b);
  k_em<<<(T_ * B_) / 64, 256, 0, stream>>>(wc, bc);
  k_decode<<<128, 64, 0, stream>>>(y, start, endw, trans, out_f);
  k_fin<<<1, 1, 0, stream>>>(out_f + (size_t)B_ * T_);
}

// Round 7
// 5322.687 us; speedup vs baseline: 1.0255x; 1.0255x over previous
//
#include <hip/hip_runtime.h>

// Problem dims
#define T_ 512
#define B_ 64
#define E_ 256
#define H_ 256
#define K_ 21
#define NSLICE 16   // workgroups per direction (16 hidden units each)

typedef short          s16x8 __attribute__((ext_vector_type(8)));
typedef unsigned short u16x4 __attribute__((ext_vector_type(4)));
typedef float          f32x4 __attribute__((ext_vector_type(4)));

// ---- module-scope device scratch (d_out is float32; d_ws unused) ----
__device__ __attribute__((aligned(16))) unsigned short g_hs[T_ * B_ * 2 * H_];  // [T][B][2H] bf16 bits
__device__ __attribute__((aligned(16))) unsigned short g_hbuf[2 * 2 * B_ * H_]; // [dir][par][B][H]
__device__ __attribute__((aligned(16))) float    g_em[T_ * B_ * K_];            // [T][B][K] f32
__device__ unsigned g_ctr[2 * T_];                                              // [dir][T]
// ---- diagnostics: every failure mode -> distinct loss-slot value ----
__device__ int   g_marker;
__device__ int   g_done_lstm;   // expect 32
__device__ int   g_done_dec;    // expect 128
__device__ int   g_timeout;
__device__ float g_sum;

__device__ __forceinline__ f32x4 mfma16(s16x8 a, s16x8 b, f32x4 c) {
  return __builtin_amdgcn_mfma_f32_16x16x32_bf16(a, b, c, 0, 0, 0);
}

// f32 -> bf16 bits, round-to-nearest-even (finite inputs only)
__device__ __forceinline__ unsigned short f2b(float f) {
  unsigned u = __float_as_uint(f);
  u = (u + 0x7fffu + ((u >> 16) & 1u)) >> 16;
  return (unsigned short)u;
}

__device__ __forceinline__ s16x8 cvt8(const float* p) {
  s16x8 v;
#pragma unroll
  for (int j = 0; j < 8; ++j) v[j] = (short)f2b(p[j]);
  return v;
}

// ---------------- K0: zero h-exchange buffers, counters, diagnostics ----------------
__global__ void k_zero() {
  int i = blockIdx.x * 256 + threadIdx.x;   // 256 x 256 = 65536 threads
  if (i < 2 * 2 * B_ * H_) g_hbuf[i] = 0;
  if (i < 2 * T_) g_ctr[i] = 0u;
  if (i == 0) {
    g_marker = 1;
    g_done_lstm = 0;
    g_done_dec = 0;
    g_timeout = 0;
    g_sum = 0.f;
  }
}

// ---------------- K1: biLSTM recurrence (MFMA, weights stationary in VGPRs) ----------
// 32 WGs: dir = wg&1, slice s = wg>>1 (16 hidden units each). 256 thr = 4 waves.
// Sync per step: producers store h (normal), RELEASE fence (wbl2), relaxed atomicAdd
// on ct[step]; consumer tid0 spins on relaxed agent-scope atomic LOADs (no RMW
// contention), then one ACQUIRE fence (inv) before reading peers' h.
__global__ __launch_bounds__(256, 1) void k_lstm(
    const int* __restrict__ x, const float* __restrict__ emb,
    const float* __restrict__ whh_f, const float* __restrict__ wih_f, const float* __restrict__ b_f,
    const float* __restrict__ whh_b, const float* __restrict__ wih_b, const float* __restrict__ b_b)
{
  const int wg  = blockIdx.x;
  const int dir = wg & 1;
  const int s   = wg >> 1;
  const int tid = threadIdx.x;
  const int lane = tid & 63;
  const int wv  = tid >> 6;      // 0..3
  const int wm  = wv & 1;        // M half (batches wm*32..+31)
  const int wn  = wv >> 1;       // N half (gate-rows wn*32..+31)
  const int l15 = lane & 15;
  const int l4  = lane >> 4;

  const float* whh  = dir ? whh_b : whh_f;
  const float* wih  = dir ? wih_b : wih_f;
  const float* bias = dir ? b_b : b_f;
  unsigned short* hb = g_hbuf + (size_t)dir * (2 * B_ * H_);
  unsigned* ct = g_ctr + dir * T_;

  // stationary weight B-fragments: n = 64 gate-rows (4 gates x 16 units), k = [h|xe] (512)
  s16x8 bfr[2][16];
#pragma unroll
  for (int ni = 0; ni < 2; ++ni) {
    int nl = (2 * wn + ni) * 16 + l15;     // 0..63
    int q = nl >> 4, j = nl & 15;          // gate, unit-within-slice
    int grow = q * H_ + s * 16 + j;        // row in [4H]
    const float* wr_h = whh + (size_t)grow * H_;
    const float* wr_i = wih + (size_t)grow * E_;
#pragma unroll
    for (int kc = 0; kc < 16; ++kc) {
      int k = kc * 32 + l4 * 8;
      const float* src = (k < H_) ? (wr_h + k) : (wr_i + (k - H_));
      bfr[ni][kc] = cvt8(src);
    }
  }

  // epilogue mapping: thread -> (batch em_m, 4 units em_jg*4..+3)
  const int em_m  = tid >> 2;
  const int em_jg = tid & 3;
  float bq[4][4];
#pragma unroll
  for (int q = 0; q < 4; ++q)
#pragma unroll
    for (int p = 0; p < 4; ++p) bq[q][p] = bias[q * H_ + s * 16 + em_jg * 4 + p];
  float cst[4] = {0.f, 0.f, 0.f, 0.f};

  __shared__ float G[64 * 65];

  const int am0 = wm * 32 + l15;        // A rows: m = lane&15 (+16 per sub-tile)
  const int am1 = wm * 32 + 16 + l15;

  // prologue: xe fragments for step 0 (A[m][k]: m = lane&15, k = (lane>>4)*8 + j)
  s16x8 xa0[8], xa1[8];
  {
    int t0 = dir ? (T_ - 1) : 0;
    int r0 = x[am0 * T_ + t0];
    int r1 = x[am1 * T_ + t0];
    const float* e0 = emb + (size_t)r0 * E_;
    const float* e1 = emb + (size_t)r1 * E_;
#pragma unroll
    for (int kc = 0; kc < 8; ++kc) {
      xa0[kc] = cvt8(e0 + kc * 32 + l4 * 8);
      xa1[kc] = cvt8(e1 + kc * 32 + l4 * 8);
    }
  }

  for (int step = 0; step < T_; ++step) {
    const int t = dir ? (T_ - 1 - step) : step;
    const int par = step & 1;

    int r0n = 0, r1n = 0;
    if (step + 1 < T_) {
      int tn = dir ? (T_ - 2 - step) : (step + 1);
      r0n = x[am0 * T_ + tn];
      r1n = x[am1 * T_ + tn];
    }

    if (step > 0) {
      if (tid == 0) {
        int it = 0;
        // contention-free poll: agent-scope atomic LOAD (cache-bypassing, no ownership)
        while (__hip_atomic_load(&ct[step - 1], __ATOMIC_RELAXED,
                                 __HIP_MEMORY_SCOPE_AGENT) < (unsigned)NSLICE) {
          __builtin_amdgcn_s_sleep(1);
          if (++it > (1 << 22)) { atomicAdd(&g_timeout, 1); break; }
        }
      }
      __syncthreads();
      __builtin_amdgcn_fence(__ATOMIC_ACQUIRE, "agent");  // inv only: see peers' h
    }

    const unsigned short* hsrc = hb + (1 - par) * (B_ * H_);
    const unsigned short* h0p = hsrc + am0 * H_ + l4 * 8;
    const unsigned short* h1p = hsrc + am1 * H_ + l4 * 8;

    f32x4 acc00 = {0,0,0,0}, acc01 = {0,0,0,0}, acc10 = {0,0,0,0}, acc11 = {0,0,0,0};
#pragma unroll
    for (int kc = 0; kc < 8; ++kc) {        // h half (k = 0..255)
      s16x8 a0 = *(const s16x8*)(h0p + kc * 32);
      s16x8 a1 = *(const s16x8*)(h1p + kc * 32);
      acc00 = mfma16(a0, bfr[0][kc], acc00);
      acc01 = mfma16(a0, bfr[1][kc], acc01);
      acc10 = mfma16(a1, bfr[0][kc], acc10);
      acc11 = mfma16(a1, bfr[1][kc], acc11);
    }
#pragma unroll
    for (int kc = 0; kc < 8; ++kc) {        // xe half (k = 256..511), prefetched
      acc00 = mfma16(xa0[kc], bfr[0][8 + kc], acc00);
      acc01 = mfma16(xa0[kc], bfr[1][8 + kc], acc01);
      acc10 = mfma16(xa1[kc], bfr[0][8 + kc], acc10);
      acc11 = mfma16(xa1[kc], bfr[1][8 + kc], acc11);
    }

    // scatter to LDS: G[m][n]; C/D layout col=lane&15, row=(lane>>4)*4+r
#pragma unroll
    for (int mi = 0; mi < 2; ++mi)
#pragma unroll
      for (int ni = 0; ni < 2; ++ni) {
        f32x4 a = (mi == 0) ? (ni == 0 ? acc00 : acc01) : (ni == 0 ? acc10 : acc11);
#pragma unroll
        for (int r = 0; r < 4; ++r) {
          int m = wm * 32 + mi * 16 + l4 * 4 + r;
          int n = (2 * wn + ni) * 16 + l15;
          G[m * 65 + n] = a[r];
        }
      }
    __syncthreads();

    // gates + state update; publish h slice to hbuf (critical) then hs (lazy)
    unsigned short* hrow = hb + par * (B_ * H_) + em_m * H_ + s * 16 + em_jg * 4;
    unsigned short* hsro = g_hs + ((size_t)t * B_ + em_m) * (2 * H_) + dir * H_ + s * 16 + em_jg * 4;
    u16x4 hv;
#pragma unroll
    for (int p = 0; p < 4; ++p) {
      int j = em_jg * 4 + p;
      float gi = G[em_m * 65 +  0 + j] + bq[0][p];
      float gf = G[em_m * 65 + 16 + j] + bq[1][p];
      float gg = G[em_m * 65 + 32 + j] + bq[2][p];
      float go = G[em_m * 65 + 48 + j] + bq[3][p];
      float ii = 1.f / (1.f + __expf(-gi));
      float ff = 1.f / (1.f + __expf(-gf));
      float gt = 1.f - 2.f / (__expf(2.f * gg) + 1.f);
      float oo = 1.f / (1.f + __expf(-go));
      float c = ff * cst[p] + ii * gt;
      cst[p] = c;
      float h = oo * (1.f - 2.f / (__expf(2.f * c) + 1.f));
      hv[p] = f2b(h);
    }
    *(u16x4*)hrow = hv;

    __syncthreads();   // drains hbuf stores (vmcnt) from all waves before release
    if (tid == 0) {
      __builtin_amdgcn_fence(__ATOMIC_RELEASE, "agent");  // wbl2 only: publish h
      atomicAdd(&ct[step], 1u);                           // device-scope RMW
    }

    // off critical path: persistent h store + xe refill for next step
    *(u16x4*)hsro = hv;
    if (step + 1 < T_) {
      const float* e0 = emb + (size_t)r0n * E_;
      const float* e1 = emb + (size_t)r1n * E_;
#pragma unroll
      for (int kc = 0; kc < 8; ++kc) {
        xa0[kc] = cvt8(e0 + kc * 32 + l4 * 8);
        xa1[kc] = cvt8(e1 + kc * 32 + l4 * 8);
      }
    }
  }

  __syncthreads();
  if (tid == 0) atomicAdd(&g_done_lstm, 1);
}

// ---------------- K2: emissions em[t][b][k] = hs @ wc^T + bc (MFMA, N padded to 32) ----
__global__ __launch_bounds__(256) void k_em(const float* __restrict__ wc,
                                            const float* __restrict__ bc) {
  const int tid = threadIdx.x;
  const int lane = tid & 63;
  const int wv = tid >> 6;
  const int l15 = lane & 15;
  const int l4 = lane >> 4;
  const int row0 = blockIdx.x * 64 + wv * 16;   // (t*64+b) row block

  s16x8 bfr[2][16];
#pragma unroll
  for (int ni = 0; ni < 2; ++ni) {
    int n = ni * 16 + l15;
#pragma unroll
    for (int kc = 0; kc < 16; ++kc) {
      s16x8 v;
      if (n < K_) {
        v = cvt8(wc + (size_t)n * (2 * H_) + kc * 32 + l4 * 8);
      } else {
#pragma unroll
        for (int jj = 0; jj < 8; ++jj) v[jj] = 0;
      }
      bfr[ni][kc] = v;
    }
  }

  f32x4 acc0 = {0,0,0,0}, acc1 = {0,0,0,0};
  const unsigned short* arow = g_hs + (size_t)(row0 + l15) * (2 * H_) + l4 * 8;
#pragma unroll
  for (int kc = 0; kc < 16; ++kc) {
    s16x8 a = *(const s16x8*)(arow + kc * 32);
    acc0 = mfma16(a, bfr[0][kc], acc0);
    acc1 = mfma16(a, bfr[1][kc], acc1);
  }
#pragma unroll
  for (int r = 0; r < 4; ++r) {
    int m = l4 * 4 + r;
    g_em[(size_t)(row0 + m) * K_ + l15] = acc0[r] + bc[l15];       // n0 = l15 < 16 < K
    int n1 = 16 + l15;
    if (n1 < K_) g_em[(size_t)(row0 + m) * K_ + n1] = acc1[r] + bc[n1];
  }
}

// ---------------- K3: decode. blocks 0..63: Viterbi tags; 64..127: CRF llh ----------------
__global__ void k_decode(const int* __restrict__ y,
                         const float* __restrict__ start, const float* __restrict__ endw,
                         const float* __restrict__ trans,
                         float* __restrict__ out_tags) {
  const int id = blockIdx.x;
  const int k = threadIdx.x;   // 64 threads = 1 wave
  const float* em = g_em;
  __shared__ float tr[K_ * K_];
  __shared__ float sc[K_];
  __shared__ unsigned char bp[T_][K_];
  __shared__ short tags[T_];
  __shared__ float zsh;

  for (int i = k; i < K_ * K_; i += 64) tr[i] = trans[i];
  __syncthreads();

  if (id < B_) {
    // ---- Viterbi (argmax ties -> first index, matching jnp.argmax) ----
    const int b = id;
    float score = 0.f;
    if (k < K_) score = start[k] + em[(size_t)b * K_ + k];
    __syncthreads();
    for (int t = 1; t < T_; ++t) {
      if (k < K_) sc[k] = score;
      __syncthreads();
      if (k < K_) {
        float e = em[(size_t)(t * B_ + b) * K_ + k];
        float best = -1e30f; int bi = 0;
        for (int k1 = 0; k1 < K_; ++k1) {
          float v = sc[k1] + tr[k1 * K_ + k];
          if (v > best) { best = v; bi = k1; }
        }
        score = best + e;
        bp[t][k] = (unsigned char)bi;
      }
      __syncthreads();
    }
    if (k < K_) sc[k] = score + endw[k];
    __syncthreads();
    if (k == 0) {
      float best = -1e30f; int bi = 0;
      for (int k1 = 0; k1 < K_; ++k1) if (sc[k1] > best) { best = sc[k1]; bi = k1; }
      short tag = (short)bi;
      tags[T_ - 1] = tag;
      for (int t = T_ - 1; t > 0; --t) { tag = (short)bp[t][tag]; tags[t - 1] = tag; }
    }
    __syncthreads();
    // OUTPUT IS FLOAT32 (reference outputs are int32/f32, not bf16)
    for (int t = k; t < T_; t += 64) out_tags[(size_t)b * T_ + t] = (float)tags[t];
    __syncthreads();
    if (k == 0) atomicAdd(&g_done_dec, 1);
  } else {
    // ---- CRF log-likelihood ----
    const int b = id - B_;
    float al = 0.f;
    if (k < K_) al = start[k] + em[(size_t)b * K_ + k];
    __syncthreads();
    for (int t = 1; t < T_; ++t) {
      if (k < K_) sc[k] = al;
      __syncthreads();
      if (k < K_) {
        float e = em[(size_t)(t * B_ + b) * K_ + k];
        float m = -1e30f;
        for (int k1 = 0; k1 < K_; ++k1) m = fmaxf(m, sc[k1] + tr[k1 * K_ + k]);
        float ssum = 0.f;
        for (int k1 = 0; k1 < K_; ++k1) ssum += __expf(sc[k1] + tr[k1 * K_ + k] - m);
        al = m + __logf(ssum) + e;
      }
      __syncthreads();
    }
    if (k < K_) sc[k] = al + endw[k];
    __syncthreads();
    if (k == 0) {
      float m = -1e30f;
      for (int k1 = 0; k1 < K_; ++k1) m = fmaxf(m, sc[k1]);
      float ssum = 0.f;
      for (int k1 = 0; k1 < K_; ++k1) ssum += __expf(sc[k1] - m);
      zsh = m + __logf(ssum);
    }
    __syncthreads();
    const int* yb = y + b * T_;
    float local = 0.f;
    for (int t = k; t < T_; t += 64) {
      if (t >= 1) {
        int y1 = yb[t], y0 = yb[t - 1];
        local += tr[y0 * K_ + y1] + em[(size_t)(t * B_ + b) * K_ + y1];
      }
    }
    for (int off = 32; off > 0; off >>= 1) local += __shfl_down(local, off, 64);
    if (k == 0) {
      int y0 = yb[0], yl = yb[T_ - 1];
      float num = local + start[y0] + em[(size_t)b * K_ + y0] + endw[yl];
      atomicAdd(&g_sum, (num - zsh) * (1.0f / 64.0f));
      atomicAdd(&g_done_dec, 1);
    }
  }
}

// ---------------- K4: finalize; encode pipeline state into the float loss slot ----------
// error map (vs ref ~ -1560): pass | 1040=timeout | 1240=sum~0 | 1440+32d=lstm
// incomplete | 4440+32d=decode incomplete | 18440=k_zero missing | 1560=nothing ran
__global__ void k_fin(float* __restrict__ out) {
  float v;
  if (g_marker != 1)             v = -20000.f;
  else if (g_done_lstm < 32)     v = -3000.f - 32.f * (float)g_done_lstm;
  else if (g_done_dec < 128)     v = -6000.f - 32.f * (float)g_done_dec;
  else if (g_timeout != 0)       v = -2600.f;
  else if (fabsf(g_sum) <= 0.5f) v = -2800.f;
  else                           v = g_sum;
  out[0] = v;
}

extern "C" void kernel_launch(void* const* d_in, const int* in_sizes, int n_in,
                              void* d_out, int out_size, void* d_ws, size_t ws_size,
                              hipStream_t stream) {
  const int*   x     = (const int*)d_in[0];
  const int*   y     = (const int*)d_in[1];
  // d_in[2] = masks: all-true by construction -> unused
  const float* emb   = (const float*)d_in[3];
  const float* wih_f = (const float*)d_in[4];
  const float* whh_f = (const float*)d_in[5];
  const float* b_f   = (const float*)d_in[6];
  const float* wih_b = (const float*)d_in[7];
  const float* whh_b = (const float*)d_in[8];
  const float* b_b   = (const float*)d_in[9];
  const float* wc    = (const float*)d_in[10];
  const float* bc    = (const float*)d_in[11];
  const float* start = (const float*)d_in[12];
  const float* endw  = (const float*)d_in[13];
  const float* trans = (const float*)d_in[14];

  float* out_f = (float*)d_out;   // float32: tags [0..B*T), loss at [B*T]

  k_zero<<<256, 256, 0, stream>>>();
  k_lstm<<<32, 256, 0, stream>>>(x, emb, whh_f, wih_f, b_f, whh_b, wih_b, b_b);
  k_em<<<(T_ * B_) / 64, 256, 0, stream>>>(wc, bc);
  k_decode<<<128, 64, 0, stream>>>(y, start, endw, trans, out_f);
  k_fin<<<1, 1, 0, stream>>>(out_f + (size_t)B_ * T_);
}